// Round 14
// baseline (150.157 us; speedup 1.0000x reference)
//
#include <hip/hip_runtime.h>

#define NUM_ITERS 500
#define LR_F 0.001f
#define VPLANE 262144    // 4*64*1024 floats
// K=1 Krylov truncation: s = d0*v0, d0 = 500*LR/||v0||.
// R22: register-direct conv WIN. R24: och-pairing WIN (114.9). R25/R27:
//      pipelining/DPP ~neutral (113.8 = session best). R26/R31: fusion closed
//      (coop API breaks graph capture; threadfence barrier ~40us/phase).
// R32: full-reduction/low-traffic restructure REGRESSED 144.6 -> traffic was
//      never the bottleneck (partials are L2/L3-resident); R32 lost on conv
//      geometry (24 FMA/load vs 48) and occupancy (1 blk/CU).
// R33 (this round): CLEAN OCCUPANCY TEST. R27 structure verbatim, ci-splits
//      doubled: conv grids 512->1024 (4 blk/CU = 4 waves/SIMD, was 2), 4 ci
//      per block, 16 partials Q/Bq/Fp, 32 for PA. launch_bounds(256,4) caps
//      VGPR 128. FMA/load ratio unchanged (16px x 2och, 6-row loads, DPP
//      halo). Only ci-grouping of sums changes (R32 proved absmax-safe).

// ---- DPP lane+-1 within 16-lane rows (boundary lanes masked by caller) ------
__device__ __forceinline__ float dpp_shr1(float v) {   // lane L <- lane L-1
  int r = __builtin_amdgcn_update_dpp(0, __float_as_int(v), 0x111, 0xf, 0xf, true);
  return __int_as_float(r);
}
__device__ __forceinline__ float dpp_shl1(float v) {   // lane L <- lane L+1
  int r = __builtin_amdgcn_update_dpp(0, __float_as_int(v), 0x101, 0xf, 0xf, true);
  return __int_as_float(r);
}

// ---- raw weight loads (wave-uniform addresses -> s_load) --------------------
__device__ __forceinline__ void wldI(const float* __restrict__ Wff,
                                     const float* __restrict__ Wb,
                                     int oc, float w[10]) {
  const float* s = Wff + (size_t)oc * 9;
#pragma unroll
  for (int k = 0; k < 9; ++k) w[k] = s[k];
  w[9] = Wb[oc];
}
__device__ __forceinline__ void wldF(const float* __restrict__ Wfb,
                                     int ci, int och, float w[10]) {
  const float* s = Wfb + ((size_t)ci * 64 + och) * 9;
#pragma unroll
  for (int k = 0; k < 9; ++k) w[k] = s[k];
  w[9] = 0.f;
}
__device__ __forceinline__ void wldZ(const float* __restrict__ Wfb,
                                     int co, int ci, float w[10]) {
  const float* s = Wfb + ((size_t)co * 64 + ci) * 9;
#pragma unroll
  for (int k = 0; k < 9; ++k) w[k] = s[8 - k];
  w[9] = 0.f;
}

// ---- load_rows6 + compute16x2 (R27 conv core, FP order unchanged) -----------
__device__ __forceinline__ void load_rows6(const float* __restrict__ plane,
                                           int strip4, int cg4, float4 r[6]) {
  int R0 = strip4 == 0 ? 0 : strip4 - 1;
  int R5 = strip4 == 28 ? 31 : strip4 + 4;
  r[0] = *(const float4*)(plane + R0 * 32 + cg4);
#pragma unroll
  for (int rr = 1; rr < 5; ++rr)
    r[rr] = *(const float4*)(plane + (strip4 + rr - 1) * 32 + cg4);
  r[5] = *(const float4*)(plane + R5 * 32 + cg4);
}

template <bool BYP, bool SCALE>
__device__ __forceinline__ void compute16x2(const float4 rin[6],
                                            const float w0[10], const float w1[10],
                                            float d0, int strip4,
                                            bool cg0, bool cg7,
                                            float acc0[16], float acc1[16],
                                            float by0[16], float by1[16]) {
  float wb0 = w0[9], wb1 = w1[9];
#pragma unroll
  for (int r = 0; r < 6; ++r) {
    float4 f4 = rin[r];
    if (r == 0) {
      bool ok = strip4 > 0;
      f4.x = ok ? f4.x : 0.f; f4.y = ok ? f4.y : 0.f;
      f4.z = ok ? f4.z : 0.f; f4.w = ok ? f4.w : 0.f;
    }
    if (r == 5) {
      bool ok = strip4 < 28;
      f4.x = ok ? f4.x : 0.f; f4.y = ok ? f4.y : 0.f;
      f4.z = ok ? f4.z : 0.f; f4.w = ok ? f4.w : 0.f;
    }
    if (SCALE) { f4.x *= d0; f4.y *= d0; f4.z *= d0; f4.w *= d0; }
    float fl = dpp_shr1(f4.w);   // lane-1's col 4cg+3 == our 4cg-1
    float fr = dpp_shl1(f4.x);   // lane+1's col 4cg   == our 4cg+4
    fl = cg0 ? 0.f : fl;
    fr = cg7 ? 0.f : fr;
    float fv[6] = {fl, f4.x, f4.y, f4.z, f4.w, fr};
#pragma unroll
    for (int k = 0; k < 4; ++k) {
      int di = r - k;
      if (di >= 0 && di < 3) {
#pragma unroll
        for (int dj = 0; dj < 3; ++dj) {
          float wv0 = w0[di * 3 + dj];
          float wv1 = w1[di * 3 + dj];
#pragma unroll
          for (int c = 0; c < 4; ++c) {
            acc0[k * 4 + c] = fmaf(fv[c + dj], wv0, acc0[k * 4 + c]);
            acc1[k * 4 + c] = fmaf(fv[c + dj], wv1, acc1[k * 4 + c]);
          }
        }
        if (BYP && di == 1) {
#pragma unroll
          for (int c = 0; c < 4; ++c) {
            by0[k * 4 + c] = fmaf(fv[c + 1], wb0, by0[k * 4 + c]);
            by1[k * 4 + c] = fmaf(fv[c + 1], wb1, by1[k * 4 + c]);
          }
        }
      }
    }
  }
}

// ---- k_init_p: partial conv3x3(x,Wff) + bypass over 4-ci slice --------------
// grid 1024 = b(2b)|ochP(4b=16)|ciS(4b=16); block 256 = 4 waves x 2 och/thread
__global__ __launch_bounds__(256, 4) void k_init_p(const float* __restrict__ x,
                                                   const float* __restrict__ Wff,
                                                   const float* __restrict__ Wb,
                                                   float* __restrict__ Q,
                                                   float* __restrict__ Bq) {
  int tid = threadIdx.x, blk = blockIdx.x;
  int ciS = blk & 15, ochP = (blk >> 4) & 15, b = blk >> 8;
  int wv = __builtin_amdgcn_readfirstlane(tid >> 6);
  int och0 = ochP * 8 + wv * 2;               // 0..126, pair (och0, och0+1)
  int strip4 = ((tid >> 3) & 7) * 4;
  int cg4 = (tid & 7) * 4;
  bool cg0 = (tid & 7) == 0, cg7 = (tid & 7) == 7;
  const float* pb = x + (size_t)(b * 64 + ciS * 4) * 1024;
  int oc0 = och0 * 64 + ciS * 4, oc1 = oc0 + 64;
  float wA0[10], wA1[10], wB0[10], wB1[10];
  float4 rA[6], rB[6];
  float acc0[16], acc1[16], by0[16], by1[16];
#pragma unroll
  for (int i = 0; i < 16; ++i) { acc0[i] = 0.f; acc1[i] = 0.f; by0[i] = 0.f; by1[i] = 0.f; }
  load_rows6(pb, strip4, cg4, rA);
  wldI(Wff, Wb, oc0, wA0);
  wldI(Wff, Wb, oc1, wA1);
  for (int ci = 0; ci < 4; ci += 2) {
    load_rows6(pb + (size_t)(ci + 1) * 1024, strip4, cg4, rB);
    wldI(Wff, Wb, oc0 + ci + 1, wB0);
    wldI(Wff, Wb, oc1 + ci + 1, wB1);
    compute16x2<true, false>(rA, wA0, wA1, 0.f, strip4, cg0, cg7, acc0, acc1, by0, by1);
    if (ci + 2 < 4) {
      load_rows6(pb + (size_t)(ci + 2) * 1024, strip4, cg4, rA);
      wldI(Wff, Wb, oc0 + ci + 2, wA0);
      wldI(Wff, Wb, oc1 + ci + 2, wA1);
    }
    compute16x2<true, false>(rB, wB0, wB1, 0.f, strip4, cg0, cg7, acc0, acc1, by0, by1);
  }
  size_t off = (size_t)ciS * 524288 + (size_t)(b * 128 + och0) * 1024 + strip4 * 32 + cg4;
#pragma unroll
  for (int k = 0; k < 4; ++k) {
    *(float4*)(Q  + off + k * 32) = {acc0[k*4], acc0[k*4+1], acc0[k*4+2], acc0[k*4+3]};
    *(float4*)(Bq + off + k * 32) = {by0[k*4],  by0[k*4+1],  by0[k*4+2],  by0[k*4+3]};
    *(float4*)(Q  + off + 1024 + k * 32) = {acc1[k*4], acc1[k*4+1], acc1[k*4+2], acc1[k*4+3]};
    *(float4*)(Bq + off + 1024 + k * 32) = {by1[k*4],  by1[k*4+1],  by1[k*4+2],  by1[k*4+3]};
  }
}

// ---- k_ysum: Y = relu(sum16 Q); out-base = Y + sum16 Bq ---------------------
__global__ __launch_bounds__(256) void k_ysum(const float* __restrict__ Q,
                                              const float* __restrict__ Bq,
                                              float* __restrict__ Y,
                                              float* __restrict__ out) {
  size_t i = (size_t)(blockIdx.x * 256 + threadIdx.x) * 4;
  float4 qs = {0.f, 0.f, 0.f, 0.f}, bs = {0.f, 0.f, 0.f, 0.f};
#pragma unroll
  for (int q = 0; q < 16; ++q) {
    float4 a = *(const float4*)(Q + (size_t)q * 524288 + i);
    float4 c = *(const float4*)(Bq + (size_t)q * 524288 + i);
    qs.x += a.x; qs.y += a.y; qs.z += a.z; qs.w += a.w;
    bs.x += c.x; bs.y += c.y; bs.z += c.z; bs.w += c.w;
  }
  qs.x = qs.x > 0.f ? qs.x : 0.f; qs.y = qs.y > 0.f ? qs.y : 0.f;
  qs.z = qs.z > 0.f ? qs.z : 0.f; qs.w = qs.w > 0.f ? qs.w : 0.f;
  *(float4*)(Y + i) = qs;
  float4 ob = {qs.x + bs.x, qs.y + bs.y, qs.z + bs.z, qs.w + bs.w};
  *(float4*)(out + i) = ob;
}

// ---- k_forward_p: partial conv3x3(Y, Wfb^T) over 4-ci slice -----------------
// grid 1024 = b(2b)|ochP(3b=8)|ciS(5b=32); 2 och/thread (och 0..63)
__global__ __launch_bounds__(256, 4) void k_forward_p(const float* __restrict__ Y,
                                                      const float* __restrict__ Wfb,
                                                      float* __restrict__ PA) {
  int tid = threadIdx.x, blk = blockIdx.x;
  int ciS = blk & 31, ochP = (blk >> 5) & 7, b = blk >> 8;
  int wv = __builtin_amdgcn_readfirstlane(tid >> 6);
  int och0 = ochP * 8 + wv * 2;               // 0..62
  int strip4 = ((tid >> 3) & 7) * 4;
  int cg4 = (tid & 7) * 4;
  bool cg0 = (tid & 7) == 0, cg7 = (tid & 7) == 7;
  const float* pb = Y + (size_t)(b * 128 + ciS * 4) * 1024;
  float wA0[10], wA1[10], wB0[10], wB1[10];
  float4 rA[6], rB[6];
  float acc0[16], acc1[16], dummy[16];
#pragma unroll
  for (int i = 0; i < 16; ++i) { acc0[i] = 0.f; acc1[i] = 0.f; }
  int ci0 = ciS * 4;
  load_rows6(pb, strip4, cg4, rA);
  wldF(Wfb, ci0, och0, wA0);
  wldF(Wfb, ci0, och0 + 1, wA1);
  for (int ci = 0; ci < 4; ci += 2) {
    load_rows6(pb + (size_t)(ci + 1) * 1024, strip4, cg4, rB);
    wldF(Wfb, ci0 + ci + 1, och0, wB0);
    wldF(Wfb, ci0 + ci + 1, och0 + 1, wB1);
    compute16x2<false, false>(rA, wA0, wA1, 0.f, strip4, cg0, cg7, acc0, acc1, dummy, dummy);
    if (ci + 2 < 4) {
      load_rows6(pb + (size_t)(ci + 2) * 1024, strip4, cg4, rA);
      wldF(Wfb, ci0 + ci + 2, och0, wA0);
      wldF(Wfb, ci0 + ci + 2, och0 + 1, wA1);
    }
    compute16x2<false, false>(rB, wB0, wB1, 0.f, strip4, cg0, cg7, acc0, acc1, dummy, dummy);
  }
  size_t off = (size_t)ciS * 262144 + (size_t)(b * 64 + och0) * 1024 + strip4 * 32 + cg4;
#pragma unroll
  for (int k = 0; k < 4; ++k) {
    *(float4*)(PA + off + k * 32) = {acc0[k*4], acc0[k*4+1], acc0[k*4+2], acc0[k*4+3]};
    *(float4*)(PA + off + 1024 + k * 32) = {acc1[k*4], acc1[k*4+1], acc1[k*4+2], acc1[k*4+3]};
  }
}

// ---- k_vnorm: v0 = x - sum32(PA); Gam[blk] = block partial of ||v0||^2 ------
__global__ __launch_bounds__(256) void k_vnorm(const float* __restrict__ x,
                                               const float* __restrict__ PA,
                                               float* __restrict__ v0out,
                                               float* __restrict__ Gam) {
  __shared__ float ws[4];
  int tid = threadIdx.x;
  size_t i = (size_t)(blockIdx.x * 256 + tid) * 4;
  float4 s = {0.f, 0.f, 0.f, 0.f};
#pragma unroll
  for (int o = 0; o < 32; ++o) {
    float4 q = *(const float4*)(PA + (size_t)o * 262144 + i);
    s.x += q.x; s.y += q.y; s.z += q.z; s.w += q.w;
  }
  float4 xv = *(const float4*)(x + i);
  float4 v = {xv.x - s.x, xv.y - s.y, xv.z - s.z, xv.w - s.w};
  *(float4*)(v0out + i) = v;
  float g = v.x * v.x + v.y * v.y + v.z * v.z + v.w * v.w;
#pragma unroll
  for (int d = 32; d; d >>= 1) g += __shfl_down(g, d, 64);
  if ((tid & 63) == 0) ws[tid >> 6] = g;
  __syncthreads();
  if (tid == 0) Gam[blockIdx.x] = ws[0] + ws[1] + ws[2] + ws[3];
}

// ---- k_finalize_p: partial conv3x3(d0*v0, flip(Wfb)) over 4-ci slice --------
// grid 1024 = b(2b)|coP(4b=16)|ciS(4b=16). Gam[256] reduced here.
__global__ __launch_bounds__(256, 4) void k_finalize_p(const float* __restrict__ V,
                                                       const float* __restrict__ Gam,
                                                       const float* __restrict__ Wfb,
                                                       float* __restrict__ Fp) {
  __shared__ float ws[4];
  int tid = threadIdx.x, blk = blockIdx.x;
  int ciS = blk & 15, coP = (blk >> 4) & 15, b = blk >> 8;
  int wv = __builtin_amdgcn_readfirstlane(tid >> 6);
  int co0 = coP * 8 + wv * 2;                 // 0..126
  int strip4 = ((tid >> 3) & 7) * 4;
  int cg4 = (tid & 7) * 4;
  bool cg0 = (tid & 7) == 0, cg7 = (tid & 7) == 7;
  // reduce Gam[0..255] -> g00 (deterministic, no atomic, no pre-zero)
  float g = Gam[tid];
#pragma unroll
  for (int d = 32; d; d >>= 1) g += __shfl_down(g, d, 64);
  if ((tid & 63) == 0) ws[tid >> 6] = g;
  __syncthreads();
  float d0 = ((float)NUM_ITERS * LR_F) *
             __builtin_amdgcn_rsqf(ws[0] + ws[1] + ws[2] + ws[3]);
  const float* pb = V + (size_t)(b * 64 + ciS * 4) * 1024;
  float wA0[10], wA1[10], wB0[10], wB1[10];
  float4 rA[6], rB[6];
  float acc0[16], acc1[16], dummy[16];
#pragma unroll
  for (int i = 0; i < 16; ++i) { acc0[i] = 0.f; acc1[i] = 0.f; }
  int civ0 = ciS * 4;
  load_rows6(pb, strip4, cg4, rA);
  wldZ(Wfb, co0, civ0, wA0);
  wldZ(Wfb, co0 + 1, civ0, wA1);
  for (int ci = 0; ci < 4; ci += 2) {
    load_rows6(pb + (size_t)(ci + 1) * 1024, strip4, cg4, rB);
    wldZ(Wfb, co0, civ0 + ci + 1, wB0);
    wldZ(Wfb, co0 + 1, civ0 + ci + 1, wB1);
    compute16x2<false, true>(rA, wA0, wA1, d0, strip4, cg0, cg7, acc0, acc1, dummy, dummy);
    if (ci + 2 < 4) {
      load_rows6(pb + (size_t)(ci + 2) * 1024, strip4, cg4, rA);
      wldZ(Wfb, co0, civ0 + ci + 2, wA0);
      wldZ(Wfb, co0 + 1, civ0 + ci + 2, wA1);
    }
    compute16x2<false, true>(rB, wB0, wB1, d0, strip4, cg0, cg7, acc0, acc1, dummy, dummy);
  }
  size_t off = (size_t)ciS * 524288 + (size_t)(b * 128 + co0) * 1024 + strip4 * 32 + cg4;
#pragma unroll
  for (int k = 0; k < 4; ++k) {
    *(float4*)(Fp + off + k * 32) = {acc0[k*4], acc0[k*4+1], acc0[k*4+2], acc0[k*4+3]};
    *(float4*)(Fp + off + 1024 + k * 32) = {acc1[k*4], acc1[k*4+1], acc1[k*4+2], acc1[k*4+3]};
  }
}

// ---- k_fsum2: out += sum16 Fp (base written by k_ysum) ----------------------
__global__ __launch_bounds__(256) void k_fsum2(const float* __restrict__ Fp,
                                               float* __restrict__ out) {
  size_t i = (size_t)(blockIdx.x * 256 + threadIdx.x) * 4;
  float4 s = *(const float4*)(out + i);
#pragma unroll
  for (int q = 0; q < 16; ++q) {
    float4 p = *(const float4*)(Fp + (size_t)q * 524288 + i);
    s.x += p.x; s.y += p.y; s.z += p.z; s.w += p.w;
  }
  *(float4*)(out + i) = s;
}

// ---- launch -----------------------------------------------------------------
extern "C" void kernel_launch(void* const* d_in, const int* in_sizes, int n_in,
                              void* d_out, int out_size, void* d_ws, size_t ws_size,
                              hipStream_t stream) {
  const float* x   = (const float*)d_in[0];
  const float* Wff = (const float*)d_in[1];
  const float* Wfb = (const float*)d_in[2];
  const float* Wb  = (const float*)d_in[3];
  float* out = (float*)d_out;

  float* V    = (float*)d_ws;                  // 262144 (v0)
  float* Gam  = V + VPLANE;                    // 256 block partials
  float* PA   = Gam + 256;                     // 32 * 262144
  float* Q    = PA + (size_t)32 * 262144;      // 16 * 524288
  float* Bq   = Q + (size_t)16 * 524288;       // 16 * 524288
  float* Fp   = Bq + (size_t)16 * 524288;      // 16 * 524288
  float* Y    = Fp + (size_t)16 * 524288;      // 524288 (relu(sum Q))

  hipLaunchKernelGGL(k_init_p,     dim3(1024), dim3(256), 0, stream, x, Wff, Wb, Q, Bq);
  hipLaunchKernelGGL(k_ysum,       dim3(512),  dim3(256), 0, stream, Q, Bq, Y, out);
  hipLaunchKernelGGL(k_forward_p,  dim3(1024), dim3(256), 0, stream, Y, Wfb, PA);
  hipLaunchKernelGGL(k_vnorm,      dim3(256),  dim3(256), 0, stream, x, PA, V, Gam);
  hipLaunchKernelGGL(k_finalize_p, dim3(1024), dim3(256), 0, stream, V, Gam, Wfb, Fp);
  hipLaunchKernelGGL(k_fsum2,      dim3(512),  dim3(256), 0, stream, Fp, out);
}

// Round 15
// 128.612 us; speedup vs baseline: 1.1675x; 1.1675x over previous
//
#include <hip/hip_runtime.h>

#define NUM_ITERS 500
#define LR_F 0.001f
#define VPLANE 262144    // 4*64*1024 floats
// K=1 Krylov truncation: s = d0*v0, d0 = 500*LR/||v0||.
// R22 register-direct WIN; R24 och-pairing WIN; R25/R27 pipelining/DPP
// ~neutral (113.8 session best). R26/R31 fusion closed. R32 traffic-
// reduction REGRESSED (traffic not the bottleneck). R33 "occupancy test"
// REGRESSED 150.2 -- but VGPR_Count=64 exposed the real cause: (256,4)
// cap + 2-och state (~115 VGPR) = scratch spilling (VALUBusy 0.37%,
// +40MB spill writes). Occupancy hypothesis still untested.
// R34 (this round): clean 4-waves/SIMD test via och/thread 2->1.
//   - Per-thread state ~115 -> fits 128-VGPR cap, NO spills.
//   - Conv grids 1024 = 4 blk/CU x 4 waves = 4 waves/SIMD (2x R27).
//   - Q/Bq/Fp layouts byte-identical to R27 (8 ci-splits); forward ciS=16
//     (PA 16 partials, vnorm sums 16). Writes unchanged vs R27.
//   - Per-och FP sequence bit-identical to R27 (pairing computed each och
//     independently) -> absmax exactly 0.015625.

// ---- DPP lane+-1 within 16-lane rows (boundary lanes masked by caller) ------
__device__ __forceinline__ float dpp_shr1(float v) {   // lane L <- lane L-1
  int r = __builtin_amdgcn_update_dpp(0, __float_as_int(v), 0x111, 0xf, 0xf, true);
  return __int_as_float(r);
}
__device__ __forceinline__ float dpp_shl1(float v) {   // lane L <- lane L+1
  int r = __builtin_amdgcn_update_dpp(0, __float_as_int(v), 0x101, 0xf, 0xf, true);
  return __int_as_float(r);
}

// ---- raw weight loads (wave-uniform addresses -> s_load) --------------------
__device__ __forceinline__ void wldI(const float* __restrict__ Wff,
                                     const float* __restrict__ Wb,
                                     int oc, float w[10]) {
  const float* s = Wff + (size_t)oc * 9;
#pragma unroll
  for (int k = 0; k < 9; ++k) w[k] = s[k];
  w[9] = Wb[oc];
}
__device__ __forceinline__ void wldF(const float* __restrict__ Wfb,
                                     int ci, int och, float w[10]) {
  const float* s = Wfb + ((size_t)ci * 64 + och) * 9;
#pragma unroll
  for (int k = 0; k < 9; ++k) w[k] = s[k];
  w[9] = 0.f;
}
__device__ __forceinline__ void wldZ(const float* __restrict__ Wfb,
                                     int co, int ci, float w[10]) {
  const float* s = Wfb + ((size_t)co * 64 + ci) * 9;
#pragma unroll
  for (int k = 0; k < 9; ++k) w[k] = s[8 - k];
  w[9] = 0.f;
}

// ---- load_rows6 + compute16x1 (R27 conv core, single och) -------------------
__device__ __forceinline__ void load_rows6(const float* __restrict__ plane,
                                           int strip4, int cg4, float4 r[6]) {
  int R0 = strip4 == 0 ? 0 : strip4 - 1;
  int R5 = strip4 == 28 ? 31 : strip4 + 4;
  r[0] = *(const float4*)(plane + R0 * 32 + cg4);
#pragma unroll
  for (int rr = 1; rr < 5; ++rr)
    r[rr] = *(const float4*)(plane + (strip4 + rr - 1) * 32 + cg4);
  r[5] = *(const float4*)(plane + R5 * 32 + cg4);
}

template <bool BYP, bool SCALE>
__device__ __forceinline__ void compute16x1(const float4 rin[6],
                                            const float w0[10],
                                            float d0, int strip4,
                                            bool cg0, bool cg7,
                                            float acc0[16], float by0[16]) {
  float wb0 = w0[9];
#pragma unroll
  for (int r = 0; r < 6; ++r) {
    float4 f4 = rin[r];
    if (r == 0) {
      bool ok = strip4 > 0;
      f4.x = ok ? f4.x : 0.f; f4.y = ok ? f4.y : 0.f;
      f4.z = ok ? f4.z : 0.f; f4.w = ok ? f4.w : 0.f;
    }
    if (r == 5) {
      bool ok = strip4 < 28;
      f4.x = ok ? f4.x : 0.f; f4.y = ok ? f4.y : 0.f;
      f4.z = ok ? f4.z : 0.f; f4.w = ok ? f4.w : 0.f;
    }
    if (SCALE) { f4.x *= d0; f4.y *= d0; f4.z *= d0; f4.w *= d0; }
    float fl = dpp_shr1(f4.w);   // lane-1's col 4cg+3 == our 4cg-1
    float fr = dpp_shl1(f4.x);   // lane+1's col 4cg   == our 4cg+4
    fl = cg0 ? 0.f : fl;
    fr = cg7 ? 0.f : fr;
    float fv[6] = {fl, f4.x, f4.y, f4.z, f4.w, fr};
#pragma unroll
    for (int k = 0; k < 4; ++k) {
      int di = r - k;
      if (di >= 0 && di < 3) {
#pragma unroll
        for (int dj = 0; dj < 3; ++dj) {
          float wv0 = w0[di * 3 + dj];
#pragma unroll
          for (int c = 0; c < 4; ++c)
            acc0[k * 4 + c] = fmaf(fv[c + dj], wv0, acc0[k * 4 + c]);
        }
        if (BYP && di == 1) {
#pragma unroll
          for (int c = 0; c < 4; ++c)
            by0[k * 4 + c] = fmaf(fv[c + 1], wb0, by0[k * 4 + c]);
        }
      }
    }
  }
}

// ---- k_init_p: partial conv3x3(x,Wff) + bypass over 8-ci octant -------------
// grid 1024 = b(2b)|ochP(5b=32)|ciO(3b=8); block 256 = 4 waves x 1 och/thread
__global__ __launch_bounds__(256, 4) void k_init_p(const float* __restrict__ x,
                                                   const float* __restrict__ Wff,
                                                   const float* __restrict__ Wb,
                                                   float* __restrict__ Q,
                                                   float* __restrict__ Bq) {
  int tid = threadIdx.x, blk = blockIdx.x;
  int ciO = blk & 7, ochP = (blk >> 3) & 31, b = blk >> 8;
  int wv = __builtin_amdgcn_readfirstlane(tid >> 6);
  int och = ochP * 4 + wv;                    // 0..127
  int strip4 = ((tid >> 3) & 7) * 4;
  int cg4 = (tid & 7) * 4;
  bool cg0 = (tid & 7) == 0, cg7 = (tid & 7) == 7;
  const float* pb = x + (size_t)(b * 64 + ciO * 8) * 1024;
  int oc0 = och * 64 + ciO * 8;
  float wA[10], wB[10];
  float4 rA[6], rB[6];
  float acc[16], by[16];
#pragma unroll
  for (int i = 0; i < 16; ++i) { acc[i] = 0.f; by[i] = 0.f; }
  load_rows6(pb, strip4, cg4, rA);
  wldI(Wff, Wb, oc0, wA);
  for (int ci = 0; ci < 8; ci += 2) {
    load_rows6(pb + (size_t)(ci + 1) * 1024, strip4, cg4, rB);
    wldI(Wff, Wb, oc0 + ci + 1, wB);
    compute16x1<true, false>(rA, wA, 0.f, strip4, cg0, cg7, acc, by);
    if (ci + 2 < 8) {
      load_rows6(pb + (size_t)(ci + 2) * 1024, strip4, cg4, rA);
      wldI(Wff, Wb, oc0 + ci + 2, wA);
    }
    compute16x1<true, false>(rB, wB, 0.f, strip4, cg0, cg7, acc, by);
  }
  size_t off = (size_t)ciO * 524288 + (size_t)(b * 128 + och) * 1024 + strip4 * 32 + cg4;
#pragma unroll
  for (int k = 0; k < 4; ++k) {
    *(float4*)(Q  + off + k * 32) = {acc[k*4], acc[k*4+1], acc[k*4+2], acc[k*4+3]};
    *(float4*)(Bq + off + k * 32) = {by[k*4],  by[k*4+1],  by[k*4+2],  by[k*4+3]};
  }
}

// ---- k_ysum: Y = relu(sum8 Q); out-base = Y + sum8 Bq -----------------------
__global__ __launch_bounds__(256) void k_ysum(const float* __restrict__ Q,
                                              const float* __restrict__ Bq,
                                              float* __restrict__ Y,
                                              float* __restrict__ out) {
  size_t i = (size_t)(blockIdx.x * 256 + threadIdx.x) * 4;
  float4 qs = {0.f, 0.f, 0.f, 0.f}, bs = {0.f, 0.f, 0.f, 0.f};
#pragma unroll
  for (int q = 0; q < 8; ++q) {
    float4 a = *(const float4*)(Q + (size_t)q * 524288 + i);
    float4 c = *(const float4*)(Bq + (size_t)q * 524288 + i);
    qs.x += a.x; qs.y += a.y; qs.z += a.z; qs.w += a.w;
    bs.x += c.x; bs.y += c.y; bs.z += c.z; bs.w += c.w;
  }
  qs.x = qs.x > 0.f ? qs.x : 0.f; qs.y = qs.y > 0.f ? qs.y : 0.f;
  qs.z = qs.z > 0.f ? qs.z : 0.f; qs.w = qs.w > 0.f ? qs.w : 0.f;
  *(float4*)(Y + i) = qs;
  float4 ob = {qs.x + bs.x, qs.y + bs.y, qs.z + bs.z, qs.w + bs.w};
  *(float4*)(out + i) = ob;
}

// ---- k_forward_p: partial conv3x3(Y, Wfb^T) over 8-ci slice -----------------
// grid 1024 = b(2b)|ochP(4b=16)|ciS(4b=16); 1 och/thread (och 0..63)
__global__ __launch_bounds__(256, 4) void k_forward_p(const float* __restrict__ Y,
                                                      const float* __restrict__ Wfb,
                                                      float* __restrict__ PA) {
  int tid = threadIdx.x, blk = blockIdx.x;
  int ciS = blk & 15, ochP = (blk >> 4) & 15, b = blk >> 8;
  int wv = __builtin_amdgcn_readfirstlane(tid >> 6);
  int och = ochP * 4 + wv;                    // 0..63
  int strip4 = ((tid >> 3) & 7) * 4;
  int cg4 = (tid & 7) * 4;
  bool cg0 = (tid & 7) == 0, cg7 = (tid & 7) == 7;
  const float* pb = Y + (size_t)(b * 128 + ciS * 8) * 1024;
  float wA[10], wB[10];
  float4 rA[6], rB[6];
  float acc[16], dummy[16];
#pragma unroll
  for (int i = 0; i < 16; ++i) acc[i] = 0.f;
  int ci0 = ciS * 8;
  load_rows6(pb, strip4, cg4, rA);
  wldF(Wfb, ci0, och, wA);
  for (int ci = 0; ci < 8; ci += 2) {
    load_rows6(pb + (size_t)(ci + 1) * 1024, strip4, cg4, rB);
    wldF(Wfb, ci0 + ci + 1, och, wB);
    compute16x1<false, false>(rA, wA, 0.f, strip4, cg0, cg7, acc, dummy);
    if (ci + 2 < 8) {
      load_rows6(pb + (size_t)(ci + 2) * 1024, strip4, cg4, rA);
      wldF(Wfb, ci0 + ci + 2, och, wA);
    }
    compute16x1<false, false>(rB, wB, 0.f, strip4, cg0, cg7, acc, dummy);
  }
  size_t off = (size_t)ciS * 262144 + (size_t)(b * 64 + och) * 1024 + strip4 * 32 + cg4;
#pragma unroll
  for (int k = 0; k < 4; ++k)
    *(float4*)(PA + off + k * 32) = {acc[k*4], acc[k*4+1], acc[k*4+2], acc[k*4+3]};
}

// ---- k_vnorm: v0 = x - sum16(PA); Gam[blk] = block partial of ||v0||^2 ------
__global__ __launch_bounds__(256) void k_vnorm(const float* __restrict__ x,
                                               const float* __restrict__ PA,
                                               float* __restrict__ v0out,
                                               float* __restrict__ Gam) {
  __shared__ float ws[4];
  int tid = threadIdx.x;
  size_t i = (size_t)(blockIdx.x * 256 + tid) * 4;
  float4 s = {0.f, 0.f, 0.f, 0.f};
#pragma unroll
  for (int o = 0; o < 16; ++o) {
    float4 q = *(const float4*)(PA + (size_t)o * 262144 + i);
    s.x += q.x; s.y += q.y; s.z += q.z; s.w += q.w;
  }
  float4 xv = *(const float4*)(x + i);
  float4 v = {xv.x - s.x, xv.y - s.y, xv.z - s.z, xv.w - s.w};
  *(float4*)(v0out + i) = v;
  float g = v.x * v.x + v.y * v.y + v.z * v.z + v.w * v.w;
#pragma unroll
  for (int d = 32; d; d >>= 1) g += __shfl_down(g, d, 64);
  if ((tid & 63) == 0) ws[tid >> 6] = g;
  __syncthreads();
  if (tid == 0) Gam[blockIdx.x] = ws[0] + ws[1] + ws[2] + ws[3];
}

// ---- k_finalize_p: partial conv3x3(d0*v0, flip(Wfb)) over 8-ci octant -------
// grid 1024 = b(2b)|coP(5b=32)|ciO(3b=8). Gam[256] reduced here.
__global__ __launch_bounds__(256, 4) void k_finalize_p(const float* __restrict__ V,
                                                       const float* __restrict__ Gam,
                                                       const float* __restrict__ Wfb,
                                                       float* __restrict__ Fp) {
  __shared__ float ws[4];
  int tid = threadIdx.x, blk = blockIdx.x;
  int ciO = blk & 7, coP = (blk >> 3) & 31, b = blk >> 8;
  int wv = __builtin_amdgcn_readfirstlane(tid >> 6);
  int co = coP * 4 + wv;                      // 0..127
  int strip4 = ((tid >> 3) & 7) * 4;
  int cg4 = (tid & 7) * 4;
  bool cg0 = (tid & 7) == 0, cg7 = (tid & 7) == 7;
  // reduce Gam[0..255] -> g00 (deterministic, no atomic, no pre-zero)
  float g = Gam[tid];
#pragma unroll
  for (int d = 32; d; d >>= 1) g += __shfl_down(g, d, 64);
  if ((tid & 63) == 0) ws[tid >> 6] = g;
  __syncthreads();
  float d0 = ((float)NUM_ITERS * LR_F) *
             __builtin_amdgcn_rsqf(ws[0] + ws[1] + ws[2] + ws[3]);
  const float* pb = V + (size_t)(b * 64 + ciO * 8) * 1024;
  float wA[10], wB[10];
  float4 rA[6], rB[6];
  float acc[16], dummy[16];
#pragma unroll
  for (int i = 0; i < 16; ++i) acc[i] = 0.f;
  int civ0 = ciO * 8;
  load_rows6(pb, strip4, cg4, rA);
  wldZ(Wfb, co, civ0, wA);
  for (int ci = 0; ci < 8; ci += 2) {
    load_rows6(pb + (size_t)(ci + 1) * 1024, strip4, cg4, rB);
    wldZ(Wfb, co, civ0 + ci + 1, wB);
    compute16x1<false, true>(rA, wA, d0, strip4, cg0, cg7, acc, dummy);
    if (ci + 2 < 8) {
      load_rows6(pb + (size_t)(ci + 2) * 1024, strip4, cg4, rA);
      wldZ(Wfb, co, civ0 + ci + 2, wA);
    }
    compute16x1<false, true>(rB, wB, d0, strip4, cg0, cg7, acc, dummy);
  }
  size_t off = (size_t)ciO * 524288 + (size_t)(b * 128 + co) * 1024 + strip4 * 32 + cg4;
#pragma unroll
  for (int k = 0; k < 4; ++k)
    *(float4*)(Fp + off + k * 32) = {acc[k*4], acc[k*4+1], acc[k*4+2], acc[k*4+3]};
}

// ---- k_fsum2: out += sum8 Fp (base written by k_ysum) -----------------------
__global__ __launch_bounds__(256) void k_fsum2(const float* __restrict__ Fp,
                                               float* __restrict__ out) {
  size_t i = (size_t)(blockIdx.x * 256 + threadIdx.x) * 4;
  float4 s = *(const float4*)(out + i);
#pragma unroll
  for (int q = 0; q < 8; ++q) {
    float4 p = *(const float4*)(Fp + (size_t)q * 524288 + i);
    s.x += p.x; s.y += p.y; s.z += p.z; s.w += p.w;
  }
  *(float4*)(out + i) = s;
}

// ---- launch -----------------------------------------------------------------
extern "C" void kernel_launch(void* const* d_in, const int* in_sizes, int n_in,
                              void* d_out, int out_size, void* d_ws, size_t ws_size,
                              hipStream_t stream) {
  const float* x   = (const float*)d_in[0];
  const float* Wff = (const float*)d_in[1];
  const float* Wfb = (const float*)d_in[2];
  const float* Wb  = (const float*)d_in[3];
  float* out = (float*)d_out;

  float* V    = (float*)d_ws;                  // 262144 (v0)
  float* Gam  = V + VPLANE;                    // 256 block partials
  float* PA   = Gam + 256;                     // 16 * 262144
  float* Q    = PA + (size_t)16 * 262144;      // 8 * 524288
  float* Bq   = Q + (size_t)8 * 524288;        // 8 * 524288
  float* Fp   = Bq + (size_t)8 * 524288;       // 8 * 524288
  float* Y    = Fp + (size_t)8 * 524288;       // 524288 (relu(sum Q))

  hipLaunchKernelGGL(k_init_p,     dim3(1024), dim3(256), 0, stream, x, Wff, Wb, Q, Bq);
  hipLaunchKernelGGL(k_ysum,       dim3(512),  dim3(256), 0, stream, Q, Bq, Y, out);
  hipLaunchKernelGGL(k_forward_p,  dim3(1024), dim3(256), 0, stream, Y, Wfb, PA);
  hipLaunchKernelGGL(k_vnorm,      dim3(256),  dim3(256), 0, stream, x, PA, V, Gam);
  hipLaunchKernelGGL(k_finalize_p, dim3(1024), dim3(256), 0, stream, V, Gam, Wfb, Fp);
  hipLaunchKernelGGL(k_fsum2,      dim3(512),  dim3(256), 0, stream, Fp, out);
}

// Round 16
// 113.615 us; speedup vs baseline: 1.3216x; 1.1320x over previous
//
#include <hip/hip_runtime.h>

#define NUM_ITERS 500
#define LR_F 0.001f
#define VPLANE 262144    // 4*64*1024 floats
// K=1 Krylov truncation: s = d0*v0, d0 = 500*LR/||v0||.
// SESSION CONVERGENCE (R35 = R27 verbatim, session best 113.8us):
// R20: k_prep removed, Gam block partials GOOD; atomic epilogue BAD.
// R21: LDS pitch-skew ~NEUTRAL. R22: register-direct conv WIN 147.7->118.4.
// R23: dword-halo + 8px/thread REGRESSED (TA pipe + lost row reuse).
// R24: och-pairing (2 och/thread) WIN 205.5->114.9.
// R25: explicit load pipeline NEUTRAL (compiler already hoists).
// R26: cooperative fusion FAILED (graph capture). R31: persistent-barrier
//      fusion REGRESSED 324 (threadfence ~40us/phase). Fusion closed.
// R27: DPP halo 113.8 = session best.
// R32: full-reduction/low-traffic REGRESSED 144.6 (traffic L2-resident,
//      never the bottleneck; lost on geometry + 1 blk/CU).
// R33: 4-wave cap with 2-och state REGRESSED 150.2 (VGPR 64 cap -> spills).
// R34: 4 waves via och=1 REGRESSED 128.6 (2x loads > occupancy gain).
// Occupancy line dead by 4 strikes; conv geometry convex around this point:
// 16px x 2och x 8ci, 2 blk/CU, register-direct, DPP halo. Latency-bound
// local minimum (VALUBusy ~10-25%); MFMA inapplicable (1.8 GFLOP total,
// residue is latency/epochs, not FLOPs).

// ---- DPP lane+-1 within 16-lane rows (boundary lanes masked by caller) ------
__device__ __forceinline__ float dpp_shr1(float v) {   // lane L <- lane L-1
  int r = __builtin_amdgcn_update_dpp(0, __float_as_int(v), 0x111, 0xf, 0xf, true);
  return __int_as_float(r);
}
__device__ __forceinline__ float dpp_shl1(float v) {   // lane L <- lane L+1
  int r = __builtin_amdgcn_update_dpp(0, __float_as_int(v), 0x101, 0xf, 0xf, true);
  return __int_as_float(r);
}

// ---- raw weight loads (wave-uniform addresses -> s_load) --------------------
__device__ __forceinline__ void wldI(const float* __restrict__ Wff,
                                     const float* __restrict__ Wb,
                                     int oc, float w[10]) {
  const float* s = Wff + (size_t)oc * 9;
#pragma unroll
  for (int k = 0; k < 9; ++k) w[k] = s[k];
  w[9] = Wb[oc];
}
__device__ __forceinline__ void wldF(const float* __restrict__ Wfb,
                                     int ci, int och, float w[10]) {
  const float* s = Wfb + ((size_t)ci * 64 + och) * 9;
#pragma unroll
  for (int k = 0; k < 9; ++k) w[k] = s[k];
  w[9] = 0.f;
}
__device__ __forceinline__ void wldZ(const float* __restrict__ Wfb,
                                     int co, int ci, float w[10]) {
  const float* s = Wfb + ((size_t)co * 64 + ci) * 9;
#pragma unroll
  for (int k = 0; k < 9; ++k) w[k] = s[8 - k];
  w[9] = 0.f;
}

// ---- load_rows6: issue the 6 row loads of one plane into registers ----------
__device__ __forceinline__ void load_rows6(const float* __restrict__ plane,
                                           int strip4, int cg4, float4 r[6]) {
  int R0 = strip4 == 0 ? 0 : strip4 - 1;
  int R5 = strip4 == 28 ? 31 : strip4 + 4;
  r[0] = *(const float4*)(plane + R0 * 32 + cg4);
#pragma unroll
  for (int rr = 1; rr < 5; ++rr)
    r[rr] = *(const float4*)(plane + (strip4 + rr - 1) * 32 + cg4);
  r[5] = *(const float4*)(plane + R5 * 32 + cg4);
}

// ---- compute16x2: taps for 16 px x 2 och from preloaded rows ---------------
template <bool BYP, bool SCALE>
__device__ __forceinline__ void compute16x2(const float4 rin[6],
                                            const float w0[10], const float w1[10],
                                            float d0, int strip4,
                                            bool cg0, bool cg7,
                                            float acc0[16], float acc1[16],
                                            float by0[16], float by1[16]) {
  float wb0 = w0[9], wb1 = w1[9];
#pragma unroll
  for (int r = 0; r < 6; ++r) {
    float4 f4 = rin[r];
    if (r == 0) {
      bool ok = strip4 > 0;
      f4.x = ok ? f4.x : 0.f; f4.y = ok ? f4.y : 0.f;
      f4.z = ok ? f4.z : 0.f; f4.w = ok ? f4.w : 0.f;
    }
    if (r == 5) {
      bool ok = strip4 < 28;
      f4.x = ok ? f4.x : 0.f; f4.y = ok ? f4.y : 0.f;
      f4.z = ok ? f4.z : 0.f; f4.w = ok ? f4.w : 0.f;
    }
    if (SCALE) { f4.x *= d0; f4.y *= d0; f4.z *= d0; f4.w *= d0; }
    float fl = dpp_shr1(f4.w);   // lane-1's col 4cg+3 == our 4cg-1
    float fr = dpp_shl1(f4.x);   // lane+1's col 4cg   == our 4cg+4
    fl = cg0 ? 0.f : fl;
    fr = cg7 ? 0.f : fr;
    float fv[6] = {fl, f4.x, f4.y, f4.z, f4.w, fr};
#pragma unroll
    for (int k = 0; k < 4; ++k) {
      int di = r - k;
      if (di >= 0 && di < 3) {
#pragma unroll
        for (int dj = 0; dj < 3; ++dj) {
          float wv0 = w0[di * 3 + dj];
          float wv1 = w1[di * 3 + dj];
#pragma unroll
          for (int c = 0; c < 4; ++c) {
            acc0[k * 4 + c] = fmaf(fv[c + dj], wv0, acc0[k * 4 + c]);
            acc1[k * 4 + c] = fmaf(fv[c + dj], wv1, acc1[k * 4 + c]);
          }
        }
        if (BYP && di == 1) {
#pragma unroll
          for (int c = 0; c < 4; ++c) {
            by0[k * 4 + c] = fmaf(fv[c + 1], wb0, by0[k * 4 + c]);
            by1[k * 4 + c] = fmaf(fv[c + 1], wb1, by1[k * 4 + c]);
          }
        }
      }
    }
  }
}

// ---- k_init_p: partial conv3x3(x,Wff) + bypass over 8-ci octant -------------
// grid 512 = b(2b)|ochP(4b)|ciO(3b); block 256 = 4 waves x 2 och/thread
__global__ __launch_bounds__(256, 2) void k_init_p(const float* __restrict__ x,
                                                   const float* __restrict__ Wff,
                                                   const float* __restrict__ Wb,
                                                   float* __restrict__ Q,
                                                   float* __restrict__ Bq) {
  int tid = threadIdx.x, blk = blockIdx.x;
  int ciO = blk & 7, ochP = (blk >> 3) & 15, b = blk >> 7;
  int wv = __builtin_amdgcn_readfirstlane(tid >> 6);
  int och0 = ochP * 8 + wv * 2;               // 0..126, pair (och0, och0+1)
  int strip4 = ((tid >> 3) & 7) * 4;
  int cg4 = (tid & 7) * 4;
  bool cg0 = (tid & 7) == 0, cg7 = (tid & 7) == 7;
  const float* pb = x + (size_t)(b * 64 + ciO * 8) * 1024;
  int oc0 = och0 * 64 + ciO * 8, oc1 = oc0 + 64;
  float wA0[10], wA1[10], wB0[10], wB1[10];
  float4 rA[6], rB[6];
  float acc0[16], acc1[16], by0[16], by1[16];
#pragma unroll
  for (int i = 0; i < 16; ++i) { acc0[i] = 0.f; acc1[i] = 0.f; by0[i] = 0.f; by1[i] = 0.f; }
  load_rows6(pb, strip4, cg4, rA);
  wldI(Wff, Wb, oc0, wA0);
  wldI(Wff, Wb, oc1, wA1);
  for (int ci = 0; ci < 8; ci += 2) {
    load_rows6(pb + (size_t)(ci + 1) * 1024, strip4, cg4, rB);
    wldI(Wff, Wb, oc0 + ci + 1, wB0);
    wldI(Wff, Wb, oc1 + ci + 1, wB1);
    compute16x2<true, false>(rA, wA0, wA1, 0.f, strip4, cg0, cg7, acc0, acc1, by0, by1);
    if (ci + 2 < 8) {
      load_rows6(pb + (size_t)(ci + 2) * 1024, strip4, cg4, rA);
      wldI(Wff, Wb, oc0 + ci + 2, wA0);
      wldI(Wff, Wb, oc1 + ci + 2, wA1);
    }
    compute16x2<true, false>(rB, wB0, wB1, 0.f, strip4, cg0, cg7, acc0, acc1, by0, by1);
  }
  size_t off = (size_t)ciO * 524288 + (size_t)(b * 128 + och0) * 1024 + strip4 * 32 + cg4;
#pragma unroll
  for (int k = 0; k < 4; ++k) {
    *(float4*)(Q  + off + k * 32) = {acc0[k*4], acc0[k*4+1], acc0[k*4+2], acc0[k*4+3]};
    *(float4*)(Bq + off + k * 32) = {by0[k*4],  by0[k*4+1],  by0[k*4+2],  by0[k*4+3]};
    *(float4*)(Q  + off + 1024 + k * 32) = {acc1[k*4], acc1[k*4+1], acc1[k*4+2], acc1[k*4+3]};
    *(float4*)(Bq + off + 1024 + k * 32) = {by1[k*4],  by1[k*4+1],  by1[k*4+2],  by1[k*4+3]};
  }
}

// ---- k_ysum: Y = relu(sum8 Q); out-base = Y + sum8 Bq -----------------------
__global__ __launch_bounds__(256) void k_ysum(const float* __restrict__ Q,
                                              const float* __restrict__ Bq,
                                              float* __restrict__ Y,
                                              float* __restrict__ out) {
  size_t i = (size_t)(blockIdx.x * 256 + threadIdx.x) * 4;
  float4 qs = {0.f, 0.f, 0.f, 0.f}, bs = {0.f, 0.f, 0.f, 0.f};
#pragma unroll
  for (int q = 0; q < 8; ++q) {
    float4 a = *(const float4*)(Q + (size_t)q * 524288 + i);
    float4 c = *(const float4*)(Bq + (size_t)q * 524288 + i);
    qs.x += a.x; qs.y += a.y; qs.z += a.z; qs.w += a.w;
    bs.x += c.x; bs.y += c.y; bs.z += c.z; bs.w += c.w;
  }
  qs.x = qs.x > 0.f ? qs.x : 0.f; qs.y = qs.y > 0.f ? qs.y : 0.f;
  qs.z = qs.z > 0.f ? qs.z : 0.f; qs.w = qs.w > 0.f ? qs.w : 0.f;
  *(float4*)(Y + i) = qs;
  float4 ob = {qs.x + bs.x, qs.y + bs.y, qs.z + bs.z, qs.w + bs.w};
  *(float4*)(out + i) = ob;
}

// ---- k_forward_p: partial conv3x3(Y, Wfb^T) over 8-ci slice -----------------
// grid 512 = b(2b)|ochP(3b)|ciS(4b); 2 och/thread (och 0..63)
__global__ __launch_bounds__(256, 2) void k_forward_p(const float* __restrict__ Y,
                                                      const float* __restrict__ Wfb,
                                                      float* __restrict__ PA) {
  int tid = threadIdx.x, blk = blockIdx.x;
  int ciS = blk & 15, ochP = (blk >> 4) & 7, b = blk >> 7;
  int wv = __builtin_amdgcn_readfirstlane(tid >> 6);
  int och0 = ochP * 8 + wv * 2;               // 0..62
  int strip4 = ((tid >> 3) & 7) * 4;
  int cg4 = (tid & 7) * 4;
  bool cg0 = (tid & 7) == 0, cg7 = (tid & 7) == 7;
  const float* pb = Y + (size_t)(b * 128 + ciS * 8) * 1024;
  float wA0[10], wA1[10], wB0[10], wB1[10];
  float4 rA[6], rB[6];
  float acc0[16], acc1[16], dummy[16];
#pragma unroll
  for (int i = 0; i < 16; ++i) { acc0[i] = 0.f; acc1[i] = 0.f; }
  int ci0 = ciS * 8;
  load_rows6(pb, strip4, cg4, rA);
  wldF(Wfb, ci0, och0, wA0);
  wldF(Wfb, ci0, och0 + 1, wA1);
  for (int ci = 0; ci < 8; ci += 2) {
    load_rows6(pb + (size_t)(ci + 1) * 1024, strip4, cg4, rB);
    wldF(Wfb, ci0 + ci + 1, och0, wB0);
    wldF(Wfb, ci0 + ci + 1, och0 + 1, wB1);
    compute16x2<false, false>(rA, wA0, wA1, 0.f, strip4, cg0, cg7, acc0, acc1, dummy, dummy);
    if (ci + 2 < 8) {
      load_rows6(pb + (size_t)(ci + 2) * 1024, strip4, cg4, rA);
      wldF(Wfb, ci0 + ci + 2, och0, wA0);
      wldF(Wfb, ci0 + ci + 2, och0 + 1, wA1);
    }
    compute16x2<false, false>(rB, wB0, wB1, 0.f, strip4, cg0, cg7, acc0, acc1, dummy, dummy);
  }
  size_t off = (size_t)ciS * 262144 + (size_t)(b * 64 + och0) * 1024 + strip4 * 32 + cg4;
#pragma unroll
  for (int k = 0; k < 4; ++k) {
    *(float4*)(PA + off + k * 32) = {acc0[k*4], acc0[k*4+1], acc0[k*4+2], acc0[k*4+3]};
    *(float4*)(PA + off + 1024 + k * 32) = {acc1[k*4], acc1[k*4+1], acc1[k*4+2], acc1[k*4+3]};
  }
}

// ---- k_vnorm: v0 = x - sum16(PA); Gam[blk] = block partial of ||v0||^2 ------
__global__ __launch_bounds__(256) void k_vnorm(const float* __restrict__ x,
                                               const float* __restrict__ PA,
                                               float* __restrict__ v0out,
                                               float* __restrict__ Gam) {
  __shared__ float ws[4];
  int tid = threadIdx.x;
  size_t i = (size_t)(blockIdx.x * 256 + tid) * 4;
  float4 s = {0.f, 0.f, 0.f, 0.f};
#pragma unroll
  for (int o = 0; o < 16; ++o) {
    float4 q = *(const float4*)(PA + (size_t)o * 262144 + i);
    s.x += q.x; s.y += q.y; s.z += q.z; s.w += q.w;
  }
  float4 xv = *(const float4*)(x + i);
  float4 v = {xv.x - s.x, xv.y - s.y, xv.z - s.z, xv.w - s.w};
  *(float4*)(v0out + i) = v;
  float g = v.x * v.x + v.y * v.y + v.z * v.z + v.w * v.w;
#pragma unroll
  for (int d = 32; d; d >>= 1) g += __shfl_down(g, d, 64);
  if ((tid & 63) == 0) ws[tid >> 6] = g;
  __syncthreads();
  if (tid == 0) Gam[blockIdx.x] = ws[0] + ws[1] + ws[2] + ws[3];
}

// ---- k_finalize_p: partial conv3x3(d0*v0, flip(Wfb)) over 8-ci octant -------
// grid 512 = b(2b)|coP(4b)|ciO(3b). Gam[256] reduced here. Writes Fp partials.
__global__ __launch_bounds__(256, 2) void k_finalize_p(const float* __restrict__ V,
                                                       const float* __restrict__ Gam,
                                                       const float* __restrict__ Wfb,
                                                       float* __restrict__ Fp) {
  __shared__ float ws[4];
  int tid = threadIdx.x, blk = blockIdx.x;
  int ciO = blk & 7, coP = (blk >> 3) & 15, b = blk >> 7;
  int wv = __builtin_amdgcn_readfirstlane(tid >> 6);
  int co0 = coP * 8 + wv * 2;                 // 0..126
  int strip4 = ((tid >> 3) & 7) * 4;
  int cg4 = (tid & 7) * 4;
  bool cg0 = (tid & 7) == 0, cg7 = (tid & 7) == 7;
  // reduce Gam[0..255] -> g00 (deterministic, no atomic, no pre-zero)
  float g = Gam[tid];
#pragma unroll
  for (int d = 32; d; d >>= 1) g += __shfl_down(g, d, 64);
  if ((tid & 63) == 0) ws[tid >> 6] = g;
  __syncthreads();
  float d0 = ((float)NUM_ITERS * LR_F) *
             __builtin_amdgcn_rsqf(ws[0] + ws[1] + ws[2] + ws[3]);
  const float* pb = V + (size_t)(b * 64 + ciO * 8) * 1024;
  float wA0[10], wA1[10], wB0[10], wB1[10];
  float4 rA[6], rB[6];
  float acc0[16], acc1[16], dummy[16];
#pragma unroll
  for (int i = 0; i < 16; ++i) { acc0[i] = 0.f; acc1[i] = 0.f; }
  int civ0 = ciO * 8;
  load_rows6(pb, strip4, cg4, rA);
  wldZ(Wfb, co0, civ0, wA0);
  wldZ(Wfb, co0 + 1, civ0, wA1);
  for (int ci = 0; ci < 8; ci += 2) {
    load_rows6(pb + (size_t)(ci + 1) * 1024, strip4, cg4, rB);
    wldZ(Wfb, co0, civ0 + ci + 1, wB0);
    wldZ(Wfb, co0 + 1, civ0 + ci + 1, wB1);
    compute16x2<false, true>(rA, wA0, wA1, d0, strip4, cg0, cg7, acc0, acc1, dummy, dummy);
    if (ci + 2 < 8) {
      load_rows6(pb + (size_t)(ci + 2) * 1024, strip4, cg4, rA);
      wldZ(Wfb, co0, civ0 + ci + 2, wA0);
      wldZ(Wfb, co0 + 1, civ0 + ci + 2, wA1);
    }
    compute16x2<false, true>(rB, wB0, wB1, d0, strip4, cg0, cg7, acc0, acc1, dummy, dummy);
  }
  size_t off = (size_t)ciO * 524288 + (size_t)(b * 128 + co0) * 1024 + strip4 * 32 + cg4;
#pragma unroll
  for (int k = 0; k < 4; ++k) {
    *(float4*)(Fp + off + k * 32) = {acc0[k*4], acc0[k*4+1], acc0[k*4+2], acc0[k*4+3]};
    *(float4*)(Fp + off + 1024 + k * 32) = {acc1[k*4], acc1[k*4+1], acc1[k*4+2], acc1[k*4+3]};
  }
}

// ---- k_fsum2: out += sum8 Fp (base written by k_ysum) -----------------------
__global__ __launch_bounds__(256) void k_fsum2(const float* __restrict__ Fp,
                                               float* __restrict__ out) {
  size_t i = (size_t)(blockIdx.x * 256 + threadIdx.x) * 4;
  float4 s = *(const float4*)(out + i);
#pragma unroll
  for (int q = 0; q < 8; ++q) {
    float4 p = *(const float4*)(Fp + (size_t)q * 524288 + i);
    s.x += p.x; s.y += p.y; s.z += p.z; s.w += p.w;
  }
  *(float4*)(out + i) = s;
}

// ---- launch -----------------------------------------------------------------
extern "C" void kernel_launch(void* const* d_in, const int* in_sizes, int n_in,
                              void* d_out, int out_size, void* d_ws, size_t ws_size,
                              hipStream_t stream) {
  const float* x   = (const float*)d_in[0];
  const float* Wff = (const float*)d_in[1];
  const float* Wfb = (const float*)d_in[2];
  const float* Wb  = (const float*)d_in[3];
  float* out = (float*)d_out;

  float* V    = (float*)d_ws;                  // 262144 (v0)
  float* Gam  = V + VPLANE;                    // 256 block partials
  float* PA   = Gam + 256;                     // 16 * 262144
  float* Q    = PA + (size_t)16 * 262144;      // 8 * 524288
  float* Bq   = Q + (size_t)8 * 524288;        // 8 * 524288
  float* Fp   = Bq + (size_t)8 * 524288;       // 8 * 524288
  float* Y    = Fp + (size_t)8 * 524288;       // 524288 (relu(sum Q))

  hipLaunchKernelGGL(k_init_p,     dim3(512), dim3(256), 0, stream, x, Wff, Wb, Q, Bq);
  hipLaunchKernelGGL(k_ysum,       dim3(512), dim3(256), 0, stream, Q, Bq, Y, out);
  hipLaunchKernelGGL(k_forward_p,  dim3(512), dim3(256), 0, stream, Y, Wfb, PA);
  hipLaunchKernelGGL(k_vnorm,      dim3(256), dim3(256), 0, stream, x, PA, V, Gam);
  hipLaunchKernelGGL(k_finalize_p, dim3(512), dim3(256), 0, stream, V, Gam, Wfb, Fp);
  hipLaunchKernelGGL(k_fsum2,      dim3(512), dim3(256), 0, stream, Fp, out);
}